// Round 6
// baseline (160.701 us; speedup 1.0000x reference)
//
#include <hip/hip_runtime.h>
#include <hip/hip_bf16.h>

#define DIM  512
#define FEAT 64
#define BATCH 2048
#define DCHUNK 16   // d-values per block = 4KB per x-row = exactly one page fully consumed

using bf16x8 = __attribute__((ext_vector_type(8))) short;
using f32x4  = __attribute__((ext_vector_type(4))) float;

__device__ inline short f2bf(float f) {
    unsigned int u = __float_as_uint(f);
    u += 0x7fffu + ((u >> 16) & 1u);
    return (short)(u >> 16);
}

__device__ inline bf16x8 cvt8(float4 a, float4 b) {
    bf16x8 r;
    r[0] = f2bf(a.x); r[1] = f2bf(a.y); r[2] = f2bf(a.z); r[3] = f2bf(a.w);
    r[4] = f2bf(b.x); r[5] = f2bf(b.y); r[6] = f2bf(b.z); r[7] = f2bf(b.w);
    return r;
}

// ---- pre-pass: W f32 [512][64][64] -> bf16 MFMA-fragment layout in ws ----
// ws[short] index = ((d*8 + g8)*64 + lane)*8, g8 = ks*4+mt.
// Fragment for lane l: rows mt*16+(l&15), k = ks*32+(l>>4)*8 .. +7.
__global__ __launch_bounds__(256)
void w_prep(const float* __restrict__ W, short* __restrict__ ws) {
    const int d = blockIdx.x;
    const int t = threadIdx.x;
    const int l = t & 63, g0 = t >> 6;
#pragma unroll
    for (int h = 0; h < 2; ++h) {
        const int g8 = g0 + h * 4;
        const int mt = g8 & 3, ks = g8 >> 2;
        const float* src = W + ((size_t)d * FEAT + mt * 16 + (l & 15)) * FEAT
                             + ks * 32 + (l >> 4) * 8;
        float4 w0 = *(const float4*)src;
        float4 w1 = *(const float4*)(src + 4);
        *(bf16x8*)(ws + ((size_t)(d * 8 + g8) * 64 + l) * 8) = cvt8(w0, w1);
    }
}

// ---- main: wave owns 16 rows, iterates 16 consecutive d (page-dense walk) ----
template<bool PRE>
__global__ __launch_bounds__(256, 4)
void split_linear_main(const float* __restrict__ x,
                       const float* __restrict__ Wf,   // used when !PRE
                       const short* __restrict__ Wb,   // used when PRE
                       const float* __restrict__ bias,
                       float* __restrict__ out)
{
    const int id   = blockIdx.x;            // 0..1023
    const int d0   = (id & 31) * DCHUNK;    // d-chunk
    const int rc   = id >> 5;               // row-chunk (64 rows)
    const int tid  = threadIdx.x;
    const int wave = tid >> 6;
    const int lane = tid & 63;
    const int lr   = lane & 15;             // batch row within tile / B-col / D-col
    const int lk   = lane >> 4;             // k-group / D row-quad
    const int row  = rc * 64 + wave * 16 + lr;

    const float* xp  = x    + ((size_t)row * DIM + d0) * FEAT + lk * 8;
    float*       op  = out  + ((size_t)row * DIM + d0) * FEAT + lk * 4;
    const float* bp  = bias + (size_t)d0 * FEAT + lk * 4;
    const short* wbp = Wb   + (size_t)d0 * 4096 + lane * 8;
    const float* wfp = Wf   + ((size_t)d0 * FEAT + lr) * FEAT + lk * 8;

    struct Buf { float4 xr[4]; bf16x8 wr[8]; f32x4 br[4]; };
    Buf A, B;

    auto LOAD = [&](Buf& Bf, int i) {
        const float* xq = xp + i * FEAT;
#pragma unroll
        for (int ks = 0; ks < 2; ++ks) {
            Bf.xr[ks * 2 + 0] = *(const float4*)(xq + ks * 32);
            Bf.xr[ks * 2 + 1] = *(const float4*)(xq + ks * 32 + 4);
        }
        if (PRE) {
            const short* wq = wbp + (size_t)i * 4096;
#pragma unroll
            for (int g = 0; g < 8; ++g)
                Bf.wr[g] = *(const bf16x8*)(wq + g * 512);
        } else {
            const float* wq = wfp + (size_t)i * 4096;
#pragma unroll
            for (int g = 0; g < 8; ++g) {
                const int mt = g & 3, ks = g >> 2;
                float4 a = *(const float4*)(wq + mt * 1024 + ks * 32);
                float4 b = *(const float4*)(wq + mt * 1024 + ks * 32 + 4);
                Bf.wr[g] = cvt8(a, b);
            }
        }
        const float* bq = bp + i * FEAT;
#pragma unroll
        for (int mt = 0; mt < 4; ++mt)
            Bf.br[mt] = *(const f32x4*)(bq + mt * 16);
    };

    auto COMP = [&](Buf& Bf, int i) {
        bf16x8 af0 = cvt8(Bf.xr[0], Bf.xr[1]);   // ks = 0
        bf16x8 af1 = cvt8(Bf.xr[2], Bf.xr[3]);   // ks = 1
        f32x4 acc[4];
#pragma unroll
        for (int mt = 0; mt < 4; ++mt) acc[mt] = Bf.br[mt];
#pragma unroll
        for (int mt = 0; mt < 4; ++mt)
            acc[mt] = __builtin_amdgcn_mfma_f32_16x16x32_bf16(Bf.wr[mt],     af0, acc[mt], 0, 0, 0);
#pragma unroll
        for (int mt = 0; mt < 4; ++mt)
            acc[mt] = __builtin_amdgcn_mfma_f32_16x16x32_bf16(Bf.wr[4 + mt], af1, acc[mt], 0, 0, 0);
        float* oq = op + i * FEAT;
#pragma unroll
        for (int mt = 0; mt < 4; ++mt)
            *(f32x4*)(oq + mt * 16) = acc[mt];
    };

    LOAD(A, 0);
#pragma unroll
    for (int i = 0; i < DCHUNK; i += 2) {
        LOAD(B, i + 1);          // prefetch d+1 while computing d
        COMP(A, i);
        if (i + 2 < DCHUNK) LOAD(A, i + 2);
        COMP(B, i + 1);
    }
}

extern "C" void kernel_launch(void* const* d_in, const int* in_sizes, int n_in,
                              void* d_out, int out_size, void* d_ws, size_t ws_size,
                              hipStream_t stream) {
    const float* x    = (const float*)d_in[0];
    const float* W    = (const float*)d_in[1];
    const float* bias = (const float*)d_in[2];
    float* out        = (float*)d_out;

    const size_t WSNEED = (size_t)DIM * 8 * 64 * 8 * sizeof(short);  // 4 MB
    dim3 block(256, 1, 1);
    dim3 grid((DIM / DCHUNK) * (BATCH / 64), 1, 1);                  // 32*32 = 1024

    if (ws_size >= WSNEED) {
        short* ws = (short*)d_ws;
        w_prep<<<dim3(DIM), block, 0, stream>>>(W, ws);
        split_linear_main<true><<<grid, block, 0, stream>>>(x, nullptr, ws, bias, out);
    } else {
        split_linear_main<false><<<grid, block, 0, stream>>>(x, W, nullptr, bias, out);
    }
}

// Round 7
// 106.038 us; speedup vs baseline: 1.5155x; 1.5155x over previous
//
#include <hip/hip_runtime.h>
#include <hip/hip_bf16.h>

#define DIM  512
#define FEAT 64
#define BATCH 2048

#define ROWS_PER_BLOCK 512
#define TILES_PER_WAVE 8   // ROWS_PER_BLOCK / (4 waves * 16 rows)
#define SLOTS 2            // per-wave x staging depth

using bf16x8 = __attribute__((ext_vector_type(8))) short;
using f32x4  = __attribute__((ext_vector_type(4))) float;

typedef __attribute__((address_space(3))) float lds_f;
typedef __attribute__((address_space(1))) const float glb_f;

__device__ inline short f2bf(float f) {
    unsigned int u = __float_as_uint(f);
    u += 0x7fffu + ((u >> 16) & 1u);
    return (short)(u >> 16);
}

__device__ inline bf16x8 cvt8(float4 a, float4 b) {
    bf16x8 r;
    r[0] = f2bf(a.x); r[1] = f2bf(a.y); r[2] = f2bf(a.z); r[3] = f2bf(a.w);
    r[4] = f2bf(b.x); r[5] = f2bf(b.y); r[6] = f2bf(b.z); r[7] = f2bf(b.w);
    return r;
}

__global__ __launch_bounds__(256, 4)
void split_linear_kernel(const float* __restrict__ x,
                         const float* __restrict__ W,
                         const float* __restrict__ bias,
                         float* __restrict__ out)
{
    // x staging: [wave][slot][16 rows][64 f32], 16B-chunk XOR(row&7)-swizzled
    __shared__ float xlds[4][SLOTS][1024];
    // out transpose buffer: [wave][16 rows][16 chunks], same XOR swizzle
    __shared__ float obuf[4][1024];
    __shared__ float blds[FEAT];

    // chunked XCD swizzle, d fastest (R4)
    const int id    = blockIdx.x;
    const int xcd   = id & 7;
    const int chunk = id >> 3;
    const int nid   = xcd * 256 + chunk;
    const int d     = nid & (DIM - 1);
    const int b0    = (nid >> 9) * ROWS_PER_BLOCK;

    const int tid  = threadIdx.x;
    const int wave = tid >> 6;
    const int lane = tid & 63;
    const int lr   = lane & 15;   // A-row (g) / B-col (batch row)
    const int lk   = lane >> 4;   // k-group / D row-quad

    if (tid < FEAT) blds[tid] = bias[(size_t)d * FEAT + tid];
    __syncthreads();              // before any stage issue (sync drains vmcnt)

    // ---- W fragments in registers (zero steady-state W traffic) ----
    bf16x8 wf[2][4];
#pragma unroll
    for (int mt = 0; mt < 4; ++mt) {
        const float* wrow = W + ((size_t)d * FEAT + mt * 16 + lr) * FEAT + lk * 8;
#pragma unroll
        for (int ks = 0; ks < 2; ++ks) {
            float4 w0 = *(const float4*)(wrow + ks * 32);
            float4 w1 = *(const float4*)(wrow + ks * 32 + 4);
            wf[ks][mt] = cvt8(w0, w1);
        }
    }

    // ---- async dense stage: 4 instrs, each 4 rows x 256B fully covered ----
    auto stage = [&](int slot, int tt) {
#pragma unroll
        for (int i = 0; i < 4; ++i) {
            const int r = i * 4 + (lane >> 4);
            const int c = (lane & 15) ^ (r & 7);   // pre-swizzled source chunk
            const float* gp = x + ((size_t)(b0 + tt * 16 + r) * DIM + d) * FEAT + c * 4;
            __builtin_amdgcn_global_load_lds((glb_f*)gp,
                                             (lds_f*)&xlds[wave][slot][i * 256],
                                             16, 0, 0);
        }
    };

    stage(0, wave);            // tile 0
    stage(1, 4 + wave);        // tile 1

#pragma unroll
    for (int t = 0; t < TILES_PER_WAVE; ++t) {
        // retire exactly stage(t); never wait on recent NT stores.
        // per-tile issue: 4 stage + 4 stores. outstanding at wait:
        // t=0:[s0,s1]=8  t=1:[s1,s2,nt0]=12  t in 2..6:[s(t),nt(t-2),s(t+1),nt(t-1)]=16
        // t=7:[s7,nt5,nt6]=12
        if (t == 0)                asm volatile("s_waitcnt vmcnt(4)"  ::: "memory");
        else if (t == 1 || t == 7) asm volatile("s_waitcnt vmcnt(8)"  ::: "memory");
        else                       asm volatile("s_waitcnt vmcnt(12)" ::: "memory");
        __builtin_amdgcn_sched_barrier(0);

        const float* sl = &xlds[wave][t & 1][0];
        float4 p0a = *(const float4*)&sl[lr * 64 + (((lk * 2 + 0) ^ (lr & 7)) << 2)];
        float4 p0b = *(const float4*)&sl[lr * 64 + (((lk * 2 + 1) ^ (lr & 7)) << 2)];
        float4 p1a = *(const float4*)&sl[lr * 64 + (((8 + lk * 2 + 0) ^ (lr & 7)) << 2)];
        float4 p1b = *(const float4*)&sl[lr * 64 + (((8 + lk * 2 + 1) ^ (lr & 7)) << 2)];

        bf16x8 af0 = cvt8(p0a, p0b);   // forces lgkm drain of slot reads
        bf16x8 af1 = cvt8(p1a, p1b);
        __builtin_amdgcn_sched_barrier(0);   // keep stage below the cvts (slot reuse!)

        if (t + 2 < TILES_PER_WAVE)
            stage(t & 1, (t + 2) * 4 + wave);   // same slot we just consumed

        f32x4 acc[4];
#pragma unroll
        for (int mt = 0; mt < 4; ++mt)
            acc[mt] = *(const f32x4*)&blds[mt * 16 + lk * 4];
#pragma unroll
        for (int mt = 0; mt < 4; ++mt)
            acc[mt] = __builtin_amdgcn_mfma_f32_16x16x32_bf16(wf[0][mt], af0, acc[mt], 0, 0, 0);
#pragma unroll
        for (int mt = 0; mt < 4; ++mt)
            acc[mt] = __builtin_amdgcn_mfma_f32_16x16x32_bf16(wf[1][mt], af1, acc[mt], 0, 0, 0);

        // ---- transpose via wave-private obuf: write swizzled ----
        // lane (lr,lk), mt holds out[row lr][g = mt*16+lk*4 ..+3] -> chunk c=mt*4+lk
#pragma unroll
        for (int mt = 0; mt < 4; ++mt) {
            const int c  = mt * 4 + lk;
            const int pc = (c & 8) | ((c & 7) ^ (lr & 7));
            *(f32x4*)&obuf[wave][lr * 64 + pc * 4] = acc[mt];
        }

        // ---- dense NT store-back: instr j covers rows j*4..+3, 1KB contiguous ----
        const int orow0 = b0 + (t * 4 + wave) * 16;
#pragma unroll
        for (int j = 0; j < 4; ++j) {
            const int rr  = j * 4 + (lane >> 4);
            const int cc  = lane & 15;
            const int pc2 = (cc & 8) | ((cc & 7) ^ (rr & 7));
            f32x4 v = *(const f32x4*)&obuf[wave][rr * 64 + pc2 * 4];
            __builtin_nontemporal_store(v,
                (f32x4*)(out + ((size_t)(orow0 + rr) * DIM + d) * FEAT + cc * 4));
        }
        __builtin_amdgcn_sched_barrier(0);   // pin stores before next tile's obuf writes
    }
}

extern "C" void kernel_launch(void* const* d_in, const int* in_sizes, int n_in,
                              void* d_out, int out_size, void* d_ws, size_t ws_size,
                              hipStream_t stream) {
    const float* x    = (const float*)d_in[0];
    const float* W    = (const float*)d_in[1];
    const float* bias = (const float*)d_in[2];
    float* out        = (float*)d_out;

    dim3 grid(DIM * (BATCH / ROWS_PER_BLOCK), 1, 1);  // 2048 blocks
    dim3 block(256, 1, 1);
    split_linear_kernel<<<grid, block, 0, stream>>>(x, W, bias, out);
}